// Round 15
// baseline (303.451 us; speedup 1.0000x reference)
//
#include <hip/hip_runtime.h>
#include <stdint.h>

#define MDIM 16384
#define NDIM 8192
#define KDIM 2048
#define KB2 1024  // packed fp4 row bytes (KDIM/2)
#define EPS32 1.1920928955078125e-07f
#define BM 256
#define BN 256
// K-tile = 128 fp4 elements = 64 bytes per row

using i32x4 = __attribute__((ext_vector_type(4))) int;
using i32x8 = __attribute__((ext_vector_type(8))) int;
using f32x4 = __attribute__((ext_vector_type(4))) float;
using f32x16 = __attribute__((ext_vector_type(16))) float;
typedef __attribute__((address_space(3))) const int8_t* lds_cptr;
typedef __attribute__((address_space(3))) int8_t* lds_ptr;

// fp4 E2M1 nibble: +1.0 = 0x2, -1.0 = 0xA
__device__ __forceinline__ uint32_t nib(float v) { return (v < 0.f) ? 0xAu : 0x2u; }

// ---------------------------------------------------------------------------
// Fused pack (fp4): blocks [0,MDIM) pack A rows + ab[m]; blocks
// [MDIM, MDIM+2048) pack B transposed + atomicMax column bound.
// ---------------------------------------------------------------------------
__global__ __launch_bounds__(256) void k_pack(const float* __restrict__ x,
                                              const float* __restrict__ W,
                                              uint8_t* __restrict__ As,
                                              uint8_t* __restrict__ Bs,
                                              float* __restrict__ ab,
                                              unsigned int* __restrict__ wbu) {
  __shared__ uint8_t sm[64 * 68];
  __shared__ float red[4][64];
  const int t = threadIdx.x;
  if (blockIdx.x < MDIM) {
    const int m = blockIdx.x;
    const float4* row = (const float4*)(x + (size_t)m * KDIM);
    const float4 v0 = row[2 * t];
    const float4 v1 = row[2 * t + 1];
    const uint32_t pk =
        nib(v0.x) | (nib(v0.y) << 4) | (nib(v0.z) << 8) | (nib(v0.w) << 12) |
        (nib(v1.x) << 16) | (nib(v1.y) << 20) | (nib(v1.z) << 24) | (nib(v1.w) << 28);
    ((uint32_t*)(As + (size_t)m * KB2))[t] = pk;
    float mx = fmaxf(fmaxf(fabsf(v0.x), fabsf(v0.y)), fmaxf(fabsf(v0.z), fabsf(v0.w)));
    mx = fmaxf(mx, fmaxf(fmaxf(fabsf(v1.x), fabsf(v1.y)), fmaxf(fabsf(v1.z), fabsf(v1.w))));
#pragma unroll
    for (int o = 32; o > 0; o >>= 1) mx = fmaxf(mx, __shfl_xor(mx, o, 64));
    if ((t & 63) == 0) red[0][t >> 6] = mx;
    __syncthreads();
    if (t == 0)
      ab[m] = fmaxf(fmaxf(red[0][0], red[0][1]), fmaxf(red[0][2], red[0][3])) + EPS32;
  } else {
    const int bid = blockIdx.x - MDIM;
    const int bd = bid & 31;  // 2048/64 d-tiles
    const int bf = bid >> 5;  // 8192/64 f-tiles
    const int d0 = bd * 64, f0 = bf * 64;
    const int fl = t & 63, dq = t >> 6;
    float mx = 0.f;
#pragma unroll
    for (int i = 0; i < 16; ++i) {
      const int dl = i * 4 + dq;
      const float v = W[(size_t)(d0 + dl) * NDIM + f0 + fl];
      sm[fl * 68 + dl] = (uint8_t)nib(v);
      mx = fmaxf(mx, fabsf(v));
    }
    red[dq][fl] = mx;
    __syncthreads();
    if (t < 64) {
      const float r = fmaxf(fmaxf(red[0][t], red[1][t]), fmaxf(red[2][t], red[3][t]));
      atomicMax(&wbu[f0 + t], __float_as_uint(r));
    }
    // writer: 64 f-rows x 32 packed bytes; thread = (row nl, 16-d chunk ch)
    const int nl = t >> 2, ch = t & 3;
    const uint8_t* s = &sm[nl * 68 + ch * 16];
    uint32_t w0 = 0, w1 = 0;
#pragma unroll
    for (int i = 0; i < 4; ++i)
      w0 |= (uint32_t)(s[2 * i] | (s[2 * i + 1] << 4)) << (8 * i);
#pragma unroll
    for (int i = 0; i < 4; ++i)
      w1 |= (uint32_t)(s[8 + 2 * i] | (s[9 + 2 * i] << 4)) << (8 * i);
    *(uint2*)(Bs + (size_t)(f0 + nl) * KB2 + (d0 >> 1) + ch * 8) = make_uint2(w0, w1);
  }
}

// ---------------------------------------------------------------------------
// MX-FP4 sign-GEMM, REG-STAGED (R13 structure, passing) + hoisted FRAG:
// one 4->8-reg widening per unique fragment (12/iter) instead of per MFMA
// operand (32/iter). 256x256 tile, 8 waves, K-tile = 128 elems (64B rows),
// 4-slot LDS ring, distance-3 prefetch. Iter N: {barrier; global_load tile
// N+3 -> regs; vmcnt(4); ds_write tile N+2 (swizzled addr); LGK ladder}.
// Swizzle: phys16Bslot = logical ^ ((row>>3)&3) (R6-clean, conflicts 0).
// C[m][n] = 0.25 * ab[m] * (wb[n]+eps) * S + bias[n]
// ---------------------------------------------------------------------------
__global__ __launch_bounds__(512, 2) void k_gemm(const uint8_t* __restrict__ As,
                                                 const uint8_t* __restrict__ Bs,
                                                 const float* __restrict__ ab,
                                                 const float* __restrict__ wbf,
                                                 const float* __restrict__ bias,
                                                 float* __restrict__ out) {
  __shared__ int8_t lds[4][32768];  // ring slot: A 16KB | B 16KB
  const int t = threadIdx.x;
  const int lane = t & 63, wid = t >> 6;
  // XCD L2-chunked remap (R5: FETCH 543->197MB). nwg=2048.
  const int bid = blockIdx.x;
  const int xcd = bid & 7;
  const int local = bid >> 3;
  const int bnin = local & 7;
  const int bml = (local >> 3) & 7;
  const int bnc = local >> 6;
  const int bm = xcd * 8 + bml;
  const int bn = bnc * 8 + bnin;
  const size_t m0 = (size_t)bm * BM, n0 = (size_t)bn * BN;
  const int wr = wid >> 2, wc = wid & 3;

  // staging: load instr c in {0,1}: 16 rows x 64B; lane L -> row c*16+(L>>2),
  // col (L&3)*16 LINEAR. Write addr carries swizzle: slot = (L&3) ^ xs(row).
  const int r4 = lane >> 2;
  const int c4 = lane & 3;
  const uint8_t* glA0 = As + (m0 + (size_t)(wid * 32 + r4)) * KB2 + c4 * 16;
  const uint8_t* glA1 = As + (m0 + (size_t)(wid * 32 + 16 + r4)) * KB2 + c4 * 16;
  const uint8_t* glB0 = Bs + (n0 + (size_t)(wid * 32 + r4)) * KB2 + c4 * 16;
  const uint8_t* glB1 = Bs + (n0 + (size_t)(wid * 32 + 16 + r4)) * KB2 + c4 * 16;
  const int xs0 = (lane >> 5) & 1;         // c=0: xs in {0,1}
  const int wsl0 = (c4 ^ xs0) * 16;
  const int wsl1 = (c4 ^ (xs0 ^ 2)) * 16;  // c=1: xs ^= 2
  const int wrowA0 = (wid * 32 + r4) * 64 + wsl0;
  const int wrowA1 = (wid * 32 + 16 + r4) * 64 + wsl1;

  // fragment reads (conflict-free): row = l31 (+32 per i), logical slot =
  // kk*2 + h, phys = logical ^ ((l31>>3)&3).
  const int l31 = lane & 31, h = lane >> 5;
  const int xs = (l31 >> 3) & 3;
  const int aoff0 = (wr * 128 + l31) * 64 + ((h ^ xs) * 16);
  const int aoff1 = (wr * 128 + l31) * 64 + (((2 + h) ^ xs) * 16);
  const int boff0 = 16384 + (wc * 64 + l31) * 64 + ((h ^ xs) * 16);
  const int boff1 = 16384 + (wc * 64 + l31) * 64 + (((2 + h) ^ xs) * 16);

  f32x16 acc[4][2];
#pragma unroll
  for (int i = 0; i < 4; ++i)
#pragma unroll
    for (int j = 0; j < 2; ++j) acc[i][j] = (f32x16){0};

  // double-buffered staging regs (E/O): tile u -> set u&1
  i32x4 sE0, sE1, sE2, sE3, sO0, sO1, sO2, sO3;

#define GLOAD(dst, p) \
  asm volatile("global_load_dwordx4 %0, %1, off" : "=v"(dst) : "v"(p))

#define GL4(u, S0, S1, S2, S3)                  \
  do {                                          \
    GLOAD(S0, glA0 + (size_t)(u) * 64);         \
    GLOAD(S1, glA1 + (size_t)(u) * 64);         \
    GLOAD(S2, glB0 + (size_t)(u) * 64);         \
    GLOAD(S3, glB1 + (size_t)(u) * 64);         \
  } while (0)

#define DSW(addr, val, OFF) \
  asm volatile("ds_write_b128 %0, %1 offset:" #OFF :: "v"(addr), "v"(val))

#define WR4(u, S0, S1, S2, S3)                              \
  do {                                                      \
    lds_ptr w0 = (lds_ptr)&lds[(u) & 3][0] + wrowA0;        \
    lds_ptr w1 = (lds_ptr)&lds[(u) & 3][0] + wrowA1;        \
    DSW(w0, S0, 0);                                         \
    DSW(w1, S1, 0);                                         \
    DSW(w0, S2, 16384);                                     \
    DSW(w1, S3, 16384);                                     \
  } while (0)

#define VMW(N)                                              \
  asm volatile("s_waitcnt vmcnt(" #N ")" ::: "memory");     \
  __builtin_amdgcn_sched_barrier(0);

#define DSR(dst, ptr, OFF) \
  asm volatile("ds_read_b128 %0, %1 offset:" #OFF : "=v"(dst) : "v"(ptr))

#define LGK(N)                                              \
  asm volatile("s_waitcnt lgkmcnt(" #N ")" ::: "memory");   \
  __builtin_amdgcn_sched_barrier(0);

#define FR(x) __builtin_shufflevector((x), (x), 0, 1, 2, 3, -1, -1, -1, -1)

// swapped operands: D rows = n (b-frag first). fmt 4/4 = fp4, scales = 1.0.
// Operands are PRE-WIDENED i32x8 (hoisted FRAG).
#define SMFMA(D, FB, FA)                                                      \
  D = __builtin_amdgcn_mfma_scale_f32_32x32x64_f8f6f4(                        \
      (FB), (FA), D, 4, 4, 0, 0x7F7F7F7F, 0, 0x7F7F7F7F)

#define MP2(I, FB0, FB1, FA) SMFMA(acc[I][0], FB0, FA); SMFMA(acc[I][1], FB1, FA)

// R11 intra-iter ladder with hoisted FRAG: 12 widenings/iter (was 32).
// The 4 ds_writes are oldest in the DS queue; LGK thresholds account for them.
#define LADDER(SLOT)                                                          \
  {                                                                           \
    const int8_t* sb = &lds[(SLOT)][0];                                       \
    lds_cptr pA0 = (lds_cptr)(sb + aoff0);                                    \
    lds_cptr pA1 = (lds_cptr)(sb + aoff1);                                    \
    lds_cptr pB0 = (lds_cptr)(sb + boff0);                                    \
    lds_cptr pB1 = (lds_cptr)(sb + boff1);                                    \
    i32x4 a0, a1, a2, a3, a4, a5, a6, a7, b0, b1, b2, b3;                     \
    DSR(a0, pA0, 0); DSR(b0, pB0, 0); DSR(b1, pB0, 2048);                     \
    DSR(a1, pA0, 2048); DSR(a2, pA0, 4096); DSR(a3, pA0, 6144);               \
    DSR(a4, pA1, 0); DSR(b2, pB1, 0); DSR(b3, pB1, 2048);                     \
    DSR(a5, pA1, 2048); DSR(a6, pA1, 4096); DSR(a7, pA1, 6144);               \
    LGK(9);                                                                   \
    i32x8 FB0 = FR(b0), FB1 = FR(b1), FA = FR(a0);                            \
    __builtin_amdgcn_s_setprio(1); MP2(0, FB0, FB1, FA);                      \
    LGK(8); FA = FR(a1); MP2(1, FB0, FB1, FA);                                \
    LGK(7); FA = FR(a2); MP2(2, FB0, FB1, FA);                                \
    LGK(6); FA = FR(a3); MP2(3, FB0, FB1, FA);                                \
    LGK(3); FB0 = FR(b2); FB1 = FR(b3); FA = FR(a4); MP2(0, FB0, FB1, FA);    \
    LGK(2); FA = FR(a5); MP2(1, FB0, FB1, FA);                                \
    LGK(1); FA = FR(a6); MP2(2, FB0, FB1, FA);                                \
    LGK(0); FA = FR(a7); MP2(3, FB0, FB1, FA);                                \
    __builtin_amdgcn_s_setprio(0);                                            \
  }

// iter TT even: loads(TT+3)->O, writes(TT+2) from E. Odd: swapped.
#define ITER_EVEN(TT, DOLOAD, VMN)                                            \
  {                                                                           \
    __builtin_amdgcn_s_barrier();                                             \
    if (DOLOAD) GL4((TT) + 3, sO0, sO1, sO2, sO3);                            \
    VMW(VMN);                                                                 \
    WR4((TT) + 2, sE0, sE1, sE2, sE3);                                        \
    LADDER((TT) & 3);                                                         \
  }
#define ITER_ODD(TT, DOLOAD, VMN)                                             \
  {                                                                           \
    __builtin_amdgcn_s_barrier();                                             \
    if (DOLOAD) GL4((TT) + 3, sE0, sE1, sE2, sE3);                            \
    VMW(VMN);                                                                 \
    WR4((TT) + 2, sO0, sO1, sO2, sO3);                                        \
    LADDER((TT) & 3);                                                         \
  }

  // prologue: tiles 0,1 -> LDS (slots 0,1); tile 2 -> reg set E
  GL4(0, sE0, sE1, sE2, sE3);
  VMW(0);
  WR4(0, sE0, sE1, sE2, sE3);
  GL4(1, sO0, sO1, sO2, sO3);
  VMW(0);
  WR4(1, sO0, sO1, sO2, sO3);
  asm volatile("s_waitcnt lgkmcnt(0)" ::: "memory");  // writes consumed regs
  GL4(2, sE0, sE1, sE2, sE3);

  for (int tt = 0; tt < 12; tt += 2) {
    ITER_EVEN(tt, 1, 4);
    ITER_ODD(tt + 1, 1, 4);
  }
  ITER_EVEN(12, 1, 4);   // loads tile 15 -> O, writes tile 14 from E
  ITER_ODD(13, 0, 0);    // writes tile 15 from O
  { __builtin_amdgcn_s_barrier(); LADDER(2); }  // tile 14
  { __builtin_amdgcn_s_barrier(); LADDER(3); }  // tile 15

  // epilogue: 32x32 C-map (swapped): m = col = l31, n = (reg&3)+8*(reg>>2)+4*h
#pragma unroll
  for (int i = 0; i < 4; ++i) {
    const size_t m = m0 + wr * 128 + i * 32 + l31;
    const float av = 0.25f * ab[m];
    float* orow = out + m * NDIM;
#pragma unroll
    for (int j = 0; j < 2; ++j) {
#pragma unroll
      for (int q = 0; q < 4; ++q) {
        const size_t nb = n0 + wc * 64 + j * 32 + q * 8 + h * 4;
        const f32x4 wv = *(const f32x4*)&wbf[nb];
        const f32x4 bv = *(const f32x4*)&bias[nb];
        f32x4 o;
        o[0] = av * ((wv[0] + EPS32) * acc[i][j][q * 4 + 0]) + bv[0];
        o[1] = av * ((wv[1] + EPS32) * acc[i][j][q * 4 + 1]) + bv[1];
        o[2] = av * ((wv[2] + EPS32) * acc[i][j][q * 4 + 2]) + bv[2];
        o[3] = av * ((wv[3] + EPS32) * acc[i][j][q * 4 + 3]) + bv[3];
        *(f32x4*)(orow + nb) = o;
      }
    }
  }
#undef ITER_EVEN
#undef ITER_ODD
#undef LADDER
#undef MP2
#undef SMFMA
#undef FR
#undef LGK
#undef DSR
#undef VMW
#undef WR4
#undef DSW
#undef GL4
#undef GLOAD
}

extern "C" void kernel_launch(void* const* d_in, const int* in_sizes, int n_in,
                              void* d_out, int out_size, void* d_ws, size_t ws_size,
                              hipStream_t stream) {
  const float* x = (const float*)d_in[0];     // (4, 4096, 2048)
  const float* W = (const float*)d_in[1];     // (2048, 8192)
  const float* bias = (const float*)d_in[2];  // (8192,)
  float* out = (float*)d_out;

  char* ws = (char*)d_ws;
  uint8_t* As = (uint8_t*)ws;                                   // 16 MiB fp4
  uint8_t* Bs = (uint8_t*)(ws + (size_t)(16u << 20));           // 8 MiB fp4
  float* ab = (float*)(ws + (size_t)(24u << 20));               // 64 KiB
  float* wb = (float*)(ws + (size_t)(24u << 20) + (1u << 16));  // 32 KiB

  (void)hipMemsetAsync(wb, 0, NDIM * sizeof(float), stream);
  k_pack<<<MDIM + (KDIM / 64) * (NDIM / 64), 256, 0, stream>>>(x, W, As, Bs, ab,
                                                               (unsigned int*)wb);
  k_gemm<<<(MDIM / BM) * (NDIM / BN), 512, 0, stream>>>(As, Bs, ab, wb, bias, out);
}